// Round 5
// baseline (415.999 us; speedup 1.0000x reference)
//
#include <hip/hip_runtime.h>
#include <hip/hip_cooperative_groups.h>

namespace cg = cooperative_groups;

#define IN_CH 128
#define OUT_CH 64
#define NEG_SLOPE 0.2f

#define BSHIFT 10       // 1024 nodes per partition
#define CEDGE 2048      // edges per bin chunk (8 units of 256)
#define CAPMAX 36864    // records per partition region (mean 32.7K + ~23 sigma)
// p0 stored as 22-bit fixed point; u64 accumulate = (cnt<<32) | sum(fx22).
#define FIX22 4194304.0f

typedef short bf16x8 __attribute__((ext_vector_type(8)));
typedef float f32x4 __attribute__((ext_vector_type(4)));
typedef unsigned long long u64;
typedef unsigned int u32;

__device__ __forceinline__ unsigned short f2bf(float f) {
  union { float f; unsigned u; } v;
  v.f = f;
  unsigned r = v.u + 0x7FFF + ((v.u >> 16) & 1);  // RNE
  return (unsigned short)(r >> 16);
}

__device__ __forceinline__ float bf2f(unsigned short h) {
  union { unsigned u; float f; } v;
  v.u = (unsigned)h << 16;
  return v.f;
}

// ---------------------------------------------------------------------------
// Single cooperative kernel, 4 phases separated by grid.sync():
//  A prep: lwt transpose + u table + zero gcur.
//  B score: si/sj/wself per node, seed wsum64=0.
//  C role-split: blocks [0,nbin) counting-sort one 2048-edge chunk each into
//    49 dst-range partitions (dv[8] held in regs across hist+score; si/sj
//    gathers issued in 4-deep sub-batches to bound register pressure —
//    round-4's 9-deep version spilled at VGPR=64); blocks [nbin,G) run the
//    bf16 MFMA GEMM into xhb. NO launch_bounds minwaves (spill trap).
//  D reduce+out: block (p,q) filters partition p's records for 64-node
//    sub-bucket q (16 per partition) into a 64-entry u64 LDS table, then
//    writes out. Per-block cost is the partition scan regardless of filter
//    width, so 16 sub-buckets = 4x the CU parallelism of 4 sub-buckets.
// ---------------------------------------------------------------------------
__global__ __launch_bounds__(256) void fused_kernel(
    const float* __restrict__ x, const float* __restrict__ emb,
    const float* __restrict__ lw, const float* __restrict__ att_i,
    const float* __restrict__ att_j, const float* __restrict__ aei,
    const float* __restrict__ aej, const int* __restrict__ esrc,
    const int* __restrict__ edst, float* __restrict__ out,
    u64* __restrict__ wsum64, float2* __restrict__ si,
    float2* __restrict__ sj, float* __restrict__ wself,
    float* __restrict__ u, unsigned short* __restrict__ lwt,
    unsigned short* __restrict__ xhb, int* __restrict__ gcur,
    u32* __restrict__ brecs, int cap, int N, int E, int nbin, int nchunk,
    int nred) {
  cg::grid_group grid = cg::this_grid();
  __shared__ u32 recs[CEDGE];  // 8 KB
  __shared__ int hist[64], scn[64], gbase[64], cur[64];
  __shared__ u64 tab[64];      // 512 B

  const int G = gridDim.x;
  const int bid = blockIdx.x;
  const int tid = threadIdx.x;
  const int wave = tid >> 6;
  const int lane = tid & 63;

  // ============================ Phase A: prep ============================
  for (int vb = bid; vb < 66; vb += G) {
    if (vb < 64) {
      int idx = vb * 256 + tid;  // 0..16383
      int k = idx >> 7;
      int c = idx & 127;
      lwt[(size_t)c * IN_CH + k] = f2bf(lw[idx]);
    } else {
      int which = vb - 64;  // 0 -> att_i, 1 -> att_j
      const float* att = which ? att_j : att_i;
      int k = tid & 127;
      int h = (tid >> 7) & 1;
      float v = 0.f;
#pragma unroll 8
      for (int d = 0; d < 64; ++d)
        v = fmaf(lw[(size_t)k * IN_CH + h * 64 + d], att[h * 64 + d], v);
      u[which * 256 + h * 128 + k] = v;
    }
  }
  if (bid == 0) gcur[tid] = 0;
  grid.sync();

  // ============================ Phase B: score ===========================
  for (int n = bid * 4 + wave; n < N; n += G * 4) {
    float x0 = x[(size_t)n * IN_CH + lane];
    float x1 = x[(size_t)n * IN_CH + 64 + lane];
    float em = emb[(size_t)n * OUT_CH + lane];

    float v_si0 = fmaf(x0, u[lane], fmaf(x1, u[64 + lane], em * aei[lane]));
    float v_si1 =
        fmaf(x0, u[128 + lane], fmaf(x1, u[192 + lane], em * aei[64 + lane]));
    float v_sj0 =
        fmaf(x0, u[256 + lane], fmaf(x1, u[320 + lane], em * aej[lane]));
    float v_sj1 =
        fmaf(x0, u[384 + lane], fmaf(x1, u[448 + lane], em * aej[64 + lane]));

#pragma unroll
    for (int off = 32; off > 0; off >>= 1) {
      v_si0 += __shfl_xor(v_si0, off, 64);
      v_si1 += __shfl_xor(v_si1, off, 64);
      v_sj0 += __shfl_xor(v_sj0, off, 64);
      v_sj1 += __shfl_xor(v_sj1, off, 64);
    }

    if (lane == 0) {
      si[n] = make_float2(v_si0, v_si1);
      sj[n] = make_float2(v_sj0, v_sj1);
      float a0 = v_si0 + v_sj0;
      float a1 = v_si1 + v_sj1;
      a0 = a0 > 0.f ? a0 : NEG_SLOPE * a0;
      a1 = a1 > 0.f ? a1 : NEG_SLOPE * a1;
      wself[n] = 1.f / (1.f + __expf(a1 - a0));
      wsum64[n] = 0ull;  // spill-fallback baseline
    }
  }
  grid.sync();

  // ===================== Phase C: bin || gemm role split =================
  if (bid < nbin) {
    // ---- bin role: grid-stride over 2048-edge chunks ----
    for (int c = bid; c < nchunk; c += nbin) {
      const long e0 = (long)c * CEDGE;
      const int cnt = (int)min((long)CEDGE, (long)E - e0);

      if (tid < 64) hist[tid] = 0;
      __syncthreads();

      // edst loaded once into regs, reused across hist + score passes
      int dv[8];
#pragma unroll
      for (int k = 0; k < 8; ++k) {
        int r = (k << 8) + tid;
        dv[k] = (r < cnt) ? edst[e0 + r] : -1;
      }
#pragma unroll
      for (int k = 0; k < 8; ++k)
        if (dv[k] >= 0) atomicAdd(&hist[dv[k] >> BSHIFT], 1);
      __syncthreads();

      // wave-0 shuffle prefix scan over 64 partitions
      if (tid < 64) {
        int h = hist[tid];
        int v = h;
#pragma unroll
        for (int off = 1; off < 64; off <<= 1) {
          int t = __shfl_up(v, off, 64);
          if (tid >= off) v += t;
        }
        int excl = v - h;
        scn[tid] = excl;
        cur[tid] = excl;
        gbase[tid] = (h > 0) ? atomicAdd(&gcur[tid], h) : 0;
      }
      __syncthreads();

      // score + scatter in 4-deep sub-batches (bounded register pressure)
#pragma unroll
      for (int hb = 0; hb < 2; ++hb) {
        float2 av[4], bv[4];
#pragma unroll
        for (int k = 0; k < 4; ++k) {
          int kk = hb * 4 + k;
          if (dv[kk] >= 0) {
            int r = (kk << 8) + tid;
            av[k] = si[esrc[e0 + r]];
            bv[k] = sj[dv[kk]];
          }
        }
#pragma unroll
        for (int k = 0; k < 4; ++k) {
          int kk = hb * 4 + k;
          if (dv[kk] >= 0) {
            float a0 = av[k].x + bv[k].x;
            float a1 = av[k].y + bv[k].y;
            a0 = a0 > 0.f ? a0 : NEG_SLOPE * a0;
            a1 = a1 > 0.f ? a1 : NEG_SLOPE * a1;
            float p0 = 1.f / (1.f + __expf(a1 - a0));
            u32 fx = (u32)fminf(p0 * FIX22 + 0.5f, 4194303.0f);  // 22-bit
            int pos = atomicAdd(&cur[dv[kk] >> BSHIFT], 1);
            recs[pos] = ((u32)(dv[kk] & 1023) << 22) | fx;
          }
        }
      }
      __syncthreads();

      // coalesced writeout; partition via 6-iter binary search over scn
#pragma unroll
      for (int k = 0; k < 8; ++k) {
        int p = (k << 8) + tid;
        if (p < cnt) {
          int lo = 0, hi = 63;
#pragma unroll
          for (int it = 0; it < 6; ++it) {
            int mid = (lo + hi + 1) >> 1;
            if (scn[mid] <= p) lo = mid; else hi = mid - 1;
          }
          int b = lo;
          int gofs = gbase[b] + (p - scn[b]);
          u32 rec = recs[p];
          if (gofs < cap) {
            brecs[(size_t)b * cap + gofs] = rec;
          } else {  // rare spill: packed u64 device atomic
            atomicAdd(&wsum64[(b << BSHIFT) + (int)(rec >> 22)],
                      (1ull << 32) | (u64)(rec & 0x3FFFFFu));
          }
        }
      }
      __syncthreads();  // recs/hist reused next chunk
    }
  } else {
    // ---- gemm role (no LDS use): xhb(bf16) = x @ lin_w ----
    const int g = bid - nbin;
    const int ngemm = G - nbin;
    const int ntiles = (N + 63) / 64;
    const int ko = (lane >> 4) * 8;
    const int ccol = lane & 15;
    for (int tile = g; tile < ntiles; tile += ngemm) {
      const int row0 = tile * 64 + wave * 16;
      int arow = row0 + (lane & 15);
      if (arow >= N) arow = N - 1;  // clamped read; stores guarded
      const float* ap = x + (size_t)arow * IN_CH + ko;
      bf16x8 a[4];
#pragma unroll
      for (int kb = 0; kb < 4; ++kb) {
        float4 f0 = *(const float4*)(ap + kb * 32);
        float4 f1 = *(const float4*)(ap + kb * 32 + 4);
        bf16x8 t;
        t[0] = (short)f2bf(f0.x); t[1] = (short)f2bf(f0.y);
        t[2] = (short)f2bf(f0.z); t[3] = (short)f2bf(f0.w);
        t[4] = (short)f2bf(f1.x); t[5] = (short)f2bf(f1.y);
        t[6] = (short)f2bf(f1.z); t[7] = (short)f2bf(f1.w);
        a[kb] = t;
      }
      const int crow0 = row0 + (lane >> 4) * 4;
#pragma unroll
      for (int nt = 0; nt < 8; ++nt) {
        f32x4 acc = {0.f, 0.f, 0.f, 0.f};
        const bf16x8* bp =
            (const bf16x8*)(lwt + (size_t)(nt * 16 + ccol) * IN_CH + ko);
        acc = __builtin_amdgcn_mfma_f32_16x16x32_bf16(a[0], bp[0], acc, 0, 0, 0);
        acc = __builtin_amdgcn_mfma_f32_16x16x32_bf16(a[1], bp[4], acc, 0, 0, 0);
        acc = __builtin_amdgcn_mfma_f32_16x16x32_bf16(a[2], bp[8], acc, 0, 0, 0);
        acc = __builtin_amdgcn_mfma_f32_16x16x32_bf16(a[3], bp[12], acc, 0, 0, 0);
#pragma unroll
        for (int rr = 0; rr < 4; ++rr) {
          int n = crow0 + rr;
          if (n < N) xhb[(size_t)n * IN_CH + nt * 16 + ccol] = f2bf(acc[rr]);
        }
      }
    }
  }
  grid.sync();

  // ========================= Phase D: reduce + out =======================
  for (int m = bid; m < nred; m += G) {
    const int p = m >> 4;   // partition
    const int q = m & 15;   // 64-node sub-bucket
    if (tid < 64) tab[tid] = 0ull;
    __syncthreads();

    const int cnt = min(gcur[p], cap);
    const u32* rp = brecs + (size_t)p * cap;
#pragma unroll 4
    for (int r = tid; r < cnt; r += 256) {
      u32 rec = rp[r];
      if ((int)(rec >> 28) == q)
        atomicAdd(&tab[(rec >> 22) & 63],
                  (1ull << 32) | (u64)(rec & 0x3FFFFFu));
    }
    __syncthreads();

    const int n0 = (p << BSHIFT) + (q << 6);
    const int nmax = min(64, N - n0);
    if (nmax > 0) {
      for (int t = tid; t < nmax * 16; t += 256) {
        int ln = t >> 4;
        int n = n0 + ln;
        int c4 = (t & 15) << 2;
        u64 acc = tab[ln] + wsum64[n];  // spill baseline shares packing
        float cnt_f = (float)(u32)(acc >> 32);
        float s0 = (float)(u32)(acc & 0xFFFFFFFFu) * (1.0f / FIX22);
        float ps = wself[n];
        float w0 = 0.5f * (s0 + ps);
        float w1 = 0.5f * ((cnt_f - s0) + (1.f - ps));
        ushort4 h0 = *(const ushort4*)&xhb[(size_t)n * IN_CH + c4];
        ushort4 h1 = *(const ushort4*)&xhb[(size_t)n * IN_CH + 64 + c4];
        float4 o;
        o.x = fmaf(bf2f(h0.x), w0, bf2f(h1.x) * w1);
        o.y = fmaf(bf2f(h0.y), w0, bf2f(h1.y) * w1);
        o.z = fmaf(bf2f(h0.z), w0, bf2f(h1.z) * w1);
        o.w = fmaf(bf2f(h0.w), w0, bf2f(h1.w) * w1);
        *(float4*)&out[(size_t)n * OUT_CH + c4] = o;
      }
    }
    __syncthreads();  // tab reused next m
  }
}

extern "C" void kernel_launch(void* const* d_in, const int* in_sizes, int n_in,
                              void* d_out, int out_size, void* d_ws,
                              size_t ws_size, hipStream_t stream) {
  const float* x = (const float*)d_in[0];
  const float* emb = (const float*)d_in[1];
  const float* lw = (const float*)d_in[2];
  const float* att_i = (const float*)d_in[3];
  const float* att_j = (const float*)d_in[4];
  const float* aei = (const float*)d_in[5];
  const float* aej = (const float*)d_in[6];
  const int* esrc = (const int*)d_in[7];
  const int* edst = (const int*)d_in[8];
  float* out = (float*)d_out;

  int N = in_sizes[0] / IN_CH;  // 50000
  int E = in_sizes[7];          // 1600000
  int nbkt = (N + 1023) >> BSHIFT;       // 49 dst partitions
  int nchunk = (E + CEDGE - 1) / CEDGE;  // 782 chunks
  int nred = nbkt * 16;                  // 784 reduce work items

  char* ws = (char*)d_ws;
  u64* wsum64 = (u64*)ws;                            // N u64
  float2* si = (float2*)(wsum64 + N);                // N float2
  float2* sj = si + N;                               // N float2
  float* wself = (float*)(sj + N);                   // N f32
  float* u = wself + N;                              // 512 f32
  unsigned short* lwt = (unsigned short*)(u + 512);  // 16384 bf16 (32 KB)
  unsigned short* xhb = lwt + 16384;                 // N*128 bf16 (12.8 MB)
  int* gcur = (int*)(xhb + (size_t)N * IN_CH);       // 256 ints
  u32* brecs = (u32*)(gcur + 256);                   // nbkt * cap u32 records

  size_t fixed = (size_t)((char*)brecs - ws);
  size_t avail = ws_size > fixed ? (ws_size - fixed) / 4 : 0;
  int cap = (int)(avail / (nbkt > 0 ? nbkt : 1));
  if (cap > CAPMAX) cap = CAPMAX;
  if (cap < 4096) cap = 4096;  // spill fallback keeps this correct anyway

  // Co-resident grid size (host-side query only; no stream ops).
  static int bpc = 0;
  if (bpc == 0) {
    int nb = 0;
    hipError_t err =
        hipOccupancyMaxActiveBlocksPerMultiprocessor(&nb, fused_kernel, 256, 0);
    if (err != hipSuccess || nb <= 0) nb = 4;
    bpc = nb > 4 ? 4 : nb;
  }
  int G = 256 * bpc;  // 1024 expected
  // If G comfortably exceeds the chunk count, give every bin block exactly
  // one chunk (no stragglers) and the rest to the gemm role.
  int nbin = (G >= nchunk + G / 8) ? nchunk : (G * 3) >> 2;

  void* args[] = {(void*)&x,     (void*)&emb,    (void*)&lw,
                  (void*)&att_i, (void*)&att_j,  (void*)&aei,
                  (void*)&aej,   (void*)&esrc,   (void*)&edst,
                  (void*)&out,   (void*)&wsum64, (void*)&si,
                  (void*)&sj,    (void*)&wself,  (void*)&u,
                  (void*)&lwt,   (void*)&xhb,    (void*)&gcur,
                  (void*)&brecs, (void*)&cap,    (void*)&N,
                  (void*)&E,     (void*)&nbin,   (void*)&nchunk,
                  (void*)&nred};
  hipLaunchCooperativeKernel((void*)fused_kernel, dim3(G), dim3(256), args, 0,
                             stream);
}

// Round 6
// 198.460 us; speedup vs baseline: 2.0961x; 2.0961x over previous
//
#include <hip/hip_runtime.h>

#define IN_CH 128
#define OUT_CH 64
#define NEG_SLOPE 0.2f

#define BSHIFT 10       // 1024 nodes per partition
#define CEDGE 1024      // edges per bin block
#define CAPMAX 36864    // records per partition (mean 32.7K + ~22 sigma)
// p0 stored as 22-bit fixed point; u64 accumulate = (cnt<<32) | sum(fx22).
#define FIX22 4194304.0f

typedef short bf16x8 __attribute__((ext_vector_type(8)));
typedef float f32x4 __attribute__((ext_vector_type(4)));
typedef unsigned long long u64;
typedef unsigned int u32;

__device__ __forceinline__ unsigned short f2bf(float f) {
  union { float f; unsigned u; } v;
  v.f = f;
  unsigned r = v.u + 0x7FFF + ((v.u >> 16) & 1);  // RNE
  return (unsigned short)(r >> 16);
}

__device__ __forceinline__ float bf2f(unsigned short h) {
  union { unsigned u; float f; } v;
  v.u = (unsigned)h << 16;
  return v.f;
}

// ---------------------------------------------------------------------------
// Kernel 1 (node): 782 blocks x 256. Per block (64 nodes):
//  - build bf16 B-table in LDS from lw (lw is L2-resident: 64 KB read/block);
//    chunk (kc,col) at LDS element (kc*128+col)*8 holds lw[kc*8..+8)[col].
//  - MFMA 64x128x128 tile: xh = x @ lw, x read ONCE (f32 -> bf16 frags).
//  - scores from the f32 accumulators: s_i[n,h] = sum_c xh[n,c]*att_i[c]
//    (+ emb dot, separate 4-thread-per-node pass) == reference formulation.
//  - writes xhb(bf16), si/sj, wself, seeds wsum64=0. Block 0 zeroes gcur.
// Replaces the prep, score and gemm kernels of the previous structure.
// ---------------------------------------------------------------------------
__global__ __launch_bounds__(256) void node_kernel(
    const float* __restrict__ x, const float* __restrict__ emb,
    const float* __restrict__ lw, const float* __restrict__ att_i,
    const float* __restrict__ att_j, const float* __restrict__ aei,
    const float* __restrict__ aej, unsigned short* __restrict__ xhb,
    float2* __restrict__ si, float2* __restrict__ sj,
    float* __restrict__ wself, u64* __restrict__ wsum64,
    int* __restrict__ gcur, int N) {
  __shared__ unsigned short blds[16384];  // 32 KB B-table
  __shared__ float sxi0[64], sxi1[64], sxj0[64], sxj1[64];  // xh-part scores
  __shared__ float sei0[64], sei1[64], sej0[64], sej1[64];  // emb-part scores

  const int bid = blockIdx.x;
  const int tid = threadIdx.x;
  const int wave = tid >> 6;
  const int lane = tid & 63;
  const int n0 = bid * 64;

  if (bid == 0 && tid < 64) gcur[tid] = 0;

  // ---- emb dot pass: 4 threads per node, 16 channels each ----
  {
    int ln = tid >> 2;
    int q = tid & 3;
    int n = n0 + ln;
    float ei0 = 0.f, ei1 = 0.f, ej0 = 0.f, ej1 = 0.f;
    if (n < N) {
      const float* ep = emb + (size_t)n * OUT_CH + q * 16;
#pragma unroll
      for (int j4 = 0; j4 < 4; ++j4) {
        float4 e4 = *(const float4*)(ep + j4 * 4);
        float vals[4] = {e4.x, e4.y, e4.z, e4.w};
#pragma unroll
        for (int j = 0; j < 4; ++j) {
          int d = q * 16 + j4 * 4 + j;
          ei0 = fmaf(vals[j], aei[d], ei0);
          ei1 = fmaf(vals[j], aei[64 + d], ei1);
          ej0 = fmaf(vals[j], aej[d], ej0);
          ej1 = fmaf(vals[j], aej[64 + d], ej1);
        }
      }
    }
#pragma unroll
    for (int off = 1; off < 4; off <<= 1) {
      ei0 += __shfl_xor(ei0, off, 64);
      ei1 += __shfl_xor(ei1, off, 64);
      ej0 += __shfl_xor(ej0, off, 64);
      ej1 += __shfl_xor(ej1, off, 64);
    }
    if (q == 0) { sei0[ln] = ei0; sei1[ln] = ei1; sej0[ln] = ej0; sej1[ln] = ej1; }
  }

  // ---- build B-table in LDS (coalesced lw reads, conflict-free writes) ----
  {
    int col = tid & 127;
    int kc2 = tid >> 7;  // 0/1: low/high half of kc range
#pragma unroll
    for (int i = 0; i < 8; ++i) {
      int kc = kc2 * 8 + i;
      bf16x8 t;
#pragma unroll
      for (int j = 0; j < 8; ++j)
        t[j] = (short)f2bf(lw[(size_t)(kc * 8 + j) * IN_CH + col]);
      *(bf16x8*)&blds[(kc * 128 + col) * 8] = t;
    }
  }
  __syncthreads();

  // ---- MFMA tile + score partials from f32 accumulators ----
  const int ccol = lane & 15;
  const int rg = lane >> 4;  // row group 0..3
  const int ko = rg * 8;
  const int row0 = n0 + wave * 16;
  int arow = row0 + ccol;
  if (arow >= N) arow = N - 1;  // clamped read; stores guarded
  const float* ap = x + (size_t)arow * IN_CH + ko;
  bf16x8 a[4];
#pragma unroll
  for (int kb = 0; kb < 4; ++kb) {
    float4 f0 = *(const float4*)(ap + kb * 32);
    float4 f1 = *(const float4*)(ap + kb * 32 + 4);
    bf16x8 t;
    t[0] = (short)f2bf(f0.x); t[1] = (short)f2bf(f0.y);
    t[2] = (short)f2bf(f0.z); t[3] = (short)f2bf(f0.w);
    t[4] = (short)f2bf(f1.x); t[5] = (short)f2bf(f1.y);
    t[6] = (short)f2bf(f1.z); t[7] = (short)f2bf(f1.w);
    a[kb] = t;
  }

  const int crow0 = row0 + rg * 4;
  const bf16x8* bls = (const bf16x8*)blds;
  float pI0[4] = {0,0,0,0}, pI1[4] = {0,0,0,0};
  float pJ0[4] = {0,0,0,0}, pJ1[4] = {0,0,0,0};
#pragma unroll
  for (int nt = 0; nt < 8; ++nt) {
    f32x4 acc = {0.f, 0.f, 0.f, 0.f};
#pragma unroll
    for (int kb = 0; kb < 4; ++kb)
      acc = __builtin_amdgcn_mfma_f32_16x16x32_bf16(
          a[kb], bls[(kb * 4 + rg) * 128 + nt * 16 + ccol], acc, 0, 0, 0);
    float ai = att_i[nt * 16 + ccol];
    float aj = att_j[nt * 16 + ccol];
#pragma unroll
    for (int rr = 0; rr < 4; ++rr) {
      int n = crow0 + rr;
      if (n < N) xhb[(size_t)n * IN_CH + nt * 16 + ccol] = f2bf(acc[rr]);
      if (nt < 4) {
        pI0[rr] = fmaf(acc[rr], ai, pI0[rr]);
        pJ0[rr] = fmaf(acc[rr], aj, pJ0[rr]);
      } else {
        pI1[rr] = fmaf(acc[rr], ai, pI1[rr]);
        pJ1[rr] = fmaf(acc[rr], aj, pJ1[rr]);
      }
    }
  }
  // reduce over the 16 columns held by this row group
#pragma unroll
  for (int off = 1; off < 16; off <<= 1) {
#pragma unroll
    for (int rr = 0; rr < 4; ++rr) {
      pI0[rr] += __shfl_xor(pI0[rr], off, 64);
      pI1[rr] += __shfl_xor(pI1[rr], off, 64);
      pJ0[rr] += __shfl_xor(pJ0[rr], off, 64);
      pJ1[rr] += __shfl_xor(pJ1[rr], off, 64);
    }
  }
  if (ccol == 0) {
#pragma unroll
    for (int rr = 0; rr < 4; ++rr) {
      int ln = wave * 16 + rg * 4 + rr;
      sxi0[ln] = pI0[rr]; sxi1[ln] = pI1[rr];
      sxj0[ln] = pJ0[rr]; sxj1[ln] = pJ1[rr];
    }
  }
  __syncthreads();

  // ---- combine + write per-node outputs ----
  if (tid < 64) {
    int n = n0 + tid;
    if (n < N) {
      float vi0 = sxi0[tid] + sei0[tid];
      float vi1 = sxi1[tid] + sei1[tid];
      float vj0 = sxj0[tid] + sej0[tid];
      float vj1 = sxj1[tid] + sej1[tid];
      si[n] = make_float2(vi0, vi1);
      sj[n] = make_float2(vj0, vj1);
      float a0 = vi0 + vj0;
      float a1 = vi1 + vj1;
      a0 = a0 > 0.f ? a0 : NEG_SLOPE * a0;
      a1 = a1 > 0.f ? a1 : NEG_SLOPE * a1;
      wself[n] = 1.f / (1.f + __expf(a1 - a0));
      wsum64[n] = 0ull;  // spill-fallback baseline
    }
  }
}

// ---------------------------------------------------------------------------
// Kernel 2 (bin): 1563 blocks, one 1024-edge chunk each, 4.3 KB LDS ->
// 8 blocks/CU. Counting-sort into 49 dst-range partitions: edst batch-loaded
// into regs (reused across hist+score), si/sj gathers 4-deep in flight,
// single-wave shuffle scan, coalesced writeout via 6-iter binary search.
// Record = (dlocal10 << 22) | fx22(p0). Overflow -> packed u64 atomic.
// ---------------------------------------------------------------------------
__global__ __launch_bounds__(256) void bin_kernel(
    const int* __restrict__ esrc, const int* __restrict__ edst,
    const float2* __restrict__ si, const float2* __restrict__ sj,
    u32* __restrict__ brecs, int* __restrict__ gcur,
    u64* __restrict__ wsum64, int cap, int E) {
  __shared__ u32 recs[CEDGE];  // 4 KB
  __shared__ int hist[64], scn[64], gbase[64], cur[64];
  const int bid = blockIdx.x;
  const int tid = threadIdx.x;

  const long e0 = (long)bid * CEDGE;
  const int cnt = (int)min((long)CEDGE, (long)E - e0);

  if (tid < 64) hist[tid] = 0;
  __syncthreads();

  int dv[4];
#pragma unroll
  for (int k = 0; k < 4; ++k) {
    int r = (k << 8) + tid;
    dv[k] = (r < cnt) ? edst[e0 + r] : -1;
  }
#pragma unroll
  for (int k = 0; k < 4; ++k)
    if (dv[k] >= 0) atomicAdd(&hist[dv[k] >> BSHIFT], 1);
  __syncthreads();

  if (tid < 64) {
    int h = hist[tid];
    int v = h;
#pragma unroll
    for (int off = 1; off < 64; off <<= 1) {
      int t = __shfl_up(v, off, 64);
      if (tid >= off) v += t;
    }
    int excl = v - h;
    scn[tid] = excl;
    cur[tid] = excl;
    gbase[tid] = (h > 0) ? atomicAdd(&gcur[tid], h) : 0;
  }
  __syncthreads();

  // gathers all in flight, then score + LDS scatter
  float2 av[4], bv[4];
#pragma unroll
  for (int k = 0; k < 4; ++k) {
    if (dv[k] >= 0) {
      int r = (k << 8) + tid;
      av[k] = si[esrc[e0 + r]];
      bv[k] = sj[dv[k]];
    }
  }
#pragma unroll
  for (int k = 0; k < 4; ++k) {
    if (dv[k] >= 0) {
      float a0 = av[k].x + bv[k].x;
      float a1 = av[k].y + bv[k].y;
      a0 = a0 > 0.f ? a0 : NEG_SLOPE * a0;
      a1 = a1 > 0.f ? a1 : NEG_SLOPE * a1;
      float p0 = 1.f / (1.f + __expf(a1 - a0));
      u32 fx = (u32)fminf(p0 * FIX22 + 0.5f, 4194303.0f);  // 22-bit
      int pos = atomicAdd(&cur[dv[k] >> BSHIFT], 1);
      recs[pos] = ((u32)(dv[k] & 1023) << 22) | fx;
    }
  }
  __syncthreads();

  // coalesced writeout; partition via 6-iter binary search over scn
#pragma unroll
  for (int k = 0; k < 4; ++k) {
    int p = (k << 8) + tid;
    if (p < cnt) {
      int lo = 0, hi = 63;
#pragma unroll
      for (int it = 0; it < 6; ++it) {
        int mid = (lo + hi + 1) >> 1;
        if (scn[mid] <= p) lo = mid; else hi = mid - 1;
      }
      int b = lo;
      int gofs = gbase[b] + (p - scn[b]);
      u32 rec = recs[p];
      if (gofs < cap) {
        brecs[(size_t)b * cap + gofs] = rec;
      } else {  // rare spill: packed u64 device atomic
        atomicAdd(&wsum64[(b << BSHIFT) + (int)(rec >> 22)],
                  (1ull << 32) | (u64)(rec & 0x3FFFFFu));
      }
    }
  }
}

// ---------------------------------------------------------------------------
// Kernel 3 (reduce + out): 784 blocks x 256. Block (p,q) filters partition
// p's records for 64-node sub-bucket q (16 per partition: per-block cost is
// the partition scan regardless of filter width, so 16 sub-buckets = 4x the
// CU parallelism), accumulates into a 64-entry u64 LDS table, then writes
// out 64 nodes from bf16 xh + weights.
// ---------------------------------------------------------------------------
__global__ __launch_bounds__(256) void reduce_out_kernel(
    const unsigned short* __restrict__ xhb, const u64* __restrict__ wsum64,
    const float* __restrict__ wself, const u32* __restrict__ brecs,
    const int* __restrict__ gcur, int cap, float* __restrict__ out, int N) {
  __shared__ u64 tab[64];
  const int bid = blockIdx.x;
  const int p = bid >> 4;   // partition 0..48
  const int q = bid & 15;   // 64-node sub-bucket
  const int tid = threadIdx.x;

  if (tid < 64) tab[tid] = 0ull;
  __syncthreads();

  const int cnt = min(gcur[p], cap);
  const u32* rp = brecs + (size_t)p * cap;
#pragma unroll 4
  for (int r = tid; r < cnt; r += 256) {
    u32 rec = rp[r];
    if ((int)(rec >> 28) == q)
      atomicAdd(&tab[(rec >> 22) & 63], (1ull << 32) | (u64)(rec & 0x3FFFFFu));
  }
  __syncthreads();

  const int n0 = (p << BSHIFT) + (q << 6);
  const int nmax = min(64, N - n0);
  if (nmax <= 0) return;
  for (int t = tid; t < nmax * 16; t += 256) {
    int ln = t >> 4;
    int n = n0 + ln;
    int c4 = (t & 15) << 2;
    u64 acc = tab[ln] + wsum64[n];  // spill baseline shares packing
    float cnt_f = (float)(u32)(acc >> 32);
    float s0 = (float)(u32)(acc & 0xFFFFFFFFu) * (1.0f / FIX22);
    float ps = wself[n];
    float w0 = 0.5f * (s0 + ps);
    float w1 = 0.5f * ((cnt_f - s0) + (1.f - ps));
    ushort4 h0 = *(const ushort4*)&xhb[(size_t)n * IN_CH + c4];
    ushort4 h1 = *(const ushort4*)&xhb[(size_t)n * IN_CH + 64 + c4];
    float4 o;
    o.x = fmaf(bf2f(h0.x), w0, bf2f(h1.x) * w1);
    o.y = fmaf(bf2f(h0.y), w0, bf2f(h1.y) * w1);
    o.z = fmaf(bf2f(h0.z), w0, bf2f(h1.z) * w1);
    o.w = fmaf(bf2f(h0.w), w0, bf2f(h1.w) * w1);
    *(float4*)&out[(size_t)n * OUT_CH + c4] = o;
  }
}

extern "C" void kernel_launch(void* const* d_in, const int* in_sizes, int n_in,
                              void* d_out, int out_size, void* d_ws,
                              size_t ws_size, hipStream_t stream) {
  const float* x = (const float*)d_in[0];
  const float* emb = (const float*)d_in[1];
  const float* lw = (const float*)d_in[2];
  const float* att_i = (const float*)d_in[3];
  const float* att_j = (const float*)d_in[4];
  const float* aei = (const float*)d_in[5];
  const float* aej = (const float*)d_in[6];
  const int* esrc = (const int*)d_in[7];
  const int* edst = (const int*)d_in[8];
  float* out = (float*)d_out;

  int N = in_sizes[0] / IN_CH;  // 50000
  int E = in_sizes[7];          // 1600000
  int nbkt = (N + 1023) >> BSHIFT;       // 49 dst partitions
  int nchunk = (E + CEDGE - 1) / CEDGE;  // 1563 bin blocks
  int ntile = (N + 63) / 64;             // 782 node blocks

  char* ws = (char*)d_ws;
  u64* wsum64 = (u64*)ws;                            // N u64
  float2* si = (float2*)(wsum64 + N);                // N float2
  float2* sj = si + N;                               // N float2
  float* wself = (float*)(sj + N);                   // N f32
  unsigned short* xhb = (unsigned short*)(wself + N);  // N*128 bf16 (12.8 MB)
  int* gcur = (int*)(xhb + (size_t)N * IN_CH);       // 64 ints
  u32* brecs = (u32*)(gcur + 64);                    // nbkt * cap records

  size_t fixed = (size_t)((char*)brecs - ws);
  size_t avail = ws_size > fixed ? (ws_size - fixed) / 4 : 0;
  int cap = (int)(avail / (nbkt > 0 ? nbkt : 1));
  if (cap > CAPMAX) cap = CAPMAX;
  if (cap < 4096) cap = 4096;  // spill fallback keeps this correct anyway

  node_kernel<<<dim3(ntile), dim3(256), 0, stream>>>(
      x, emb, lw, att_i, att_j, aei, aej, xhb, si, sj, wself, wsum64, gcur, N);
  bin_kernel<<<dim3(nchunk), dim3(256), 0, stream>>>(esrc, edst, si, sj, brecs,
                                                     gcur, wsum64, cap, E);
  reduce_out_kernel<<<dim3(nbkt * 16), dim3(256), 0, stream>>>(
      xhb, wsum64, wself, brecs, gcur, cap, out, N);
}

// Round 7
// 186.333 us; speedup vs baseline: 2.2326x; 1.0651x over previous
//
#include <hip/hip_runtime.h>

#define IN_CH 128
#define OUT_CH 64
#define NEG_SLOPE 0.2f

#define BSHIFT 10       // 1024 nodes per partition
#define CEDGE 1024      // edges per bin block
#define CAPMAX 36864    // records per partition (mean 32.7K + ~22 sigma)
// p0 stored as 22-bit fixed point; u64 accumulate = (cnt<<32) | sum(fx22).
#define FIX22 4194304.0f

typedef short bf16x8 __attribute__((ext_vector_type(8)));
typedef float f32x4 __attribute__((ext_vector_type(4)));
typedef unsigned long long u64;
typedef unsigned int u32;

__device__ __forceinline__ unsigned short f2bf(float f) {
  union { float f; unsigned u; } v;
  v.f = f;
  unsigned r = v.u + 0x7FFF + ((v.u >> 16) & 1);  // RNE
  return (unsigned short)(r >> 16);
}

__device__ __forceinline__ float bf2f(unsigned short h) {
  union { unsigned u; float f; } v;
  v.u = (unsigned)h << 16;
  return v.f;
}

// ---------------------------------------------------------------------------
// Kernel 1 (node): 782 blocks x 256. Per block (64 nodes):
//  - build bf16 B-table in LDS from lw (L2-resident).
//  - MFMA 64x128x128 tile: xh = x @ lw, x read ONCE.
//  - scores from the f32 accumulators + emb dot pass.
//  - writes xhb(bf16), si/sj, wself, seeds wsum64=0. Block 0 zeroes gcur.
// (unchanged from round 6 — verified passing)
// ---------------------------------------------------------------------------
__global__ __launch_bounds__(256) void node_kernel(
    const float* __restrict__ x, const float* __restrict__ emb,
    const float* __restrict__ lw, const float* __restrict__ att_i,
    const float* __restrict__ att_j, const float* __restrict__ aei,
    const float* __restrict__ aej, unsigned short* __restrict__ xhb,
    float2* __restrict__ si, float2* __restrict__ sj,
    float* __restrict__ wself, u64* __restrict__ wsum64,
    int* __restrict__ gcur, int N) {
  __shared__ unsigned short blds[16384];  // 32 KB B-table
  __shared__ float sxi0[64], sxi1[64], sxj0[64], sxj1[64];  // xh-part scores
  __shared__ float sei0[64], sei1[64], sej0[64], sej1[64];  // emb-part scores

  const int bid = blockIdx.x;
  const int tid = threadIdx.x;
  const int wave = tid >> 6;
  const int lane = tid & 63;
  const int n0 = bid * 64;

  if (bid == 0 && tid < 64) gcur[tid] = 0;

  // ---- emb dot pass: 4 threads per node, 16 channels each ----
  {
    int ln = tid >> 2;
    int q = tid & 3;
    int n = n0 + ln;
    float ei0 = 0.f, ei1 = 0.f, ej0 = 0.f, ej1 = 0.f;
    if (n < N) {
      const float* ep = emb + (size_t)n * OUT_CH + q * 16;
#pragma unroll
      for (int j4 = 0; j4 < 4; ++j4) {
        float4 e4 = *(const float4*)(ep + j4 * 4);
        float vals[4] = {e4.x, e4.y, e4.z, e4.w};
#pragma unroll
        for (int j = 0; j < 4; ++j) {
          int d = q * 16 + j4 * 4 + j;
          ei0 = fmaf(vals[j], aei[d], ei0);
          ei1 = fmaf(vals[j], aei[64 + d], ei1);
          ej0 = fmaf(vals[j], aej[d], ej0);
          ej1 = fmaf(vals[j], aej[64 + d], ej1);
        }
      }
    }
#pragma unroll
    for (int off = 1; off < 4; off <<= 1) {
      ei0 += __shfl_xor(ei0, off, 64);
      ei1 += __shfl_xor(ei1, off, 64);
      ej0 += __shfl_xor(ej0, off, 64);
      ej1 += __shfl_xor(ej1, off, 64);
    }
    if (q == 0) { sei0[ln] = ei0; sei1[ln] = ei1; sej0[ln] = ej0; sej1[ln] = ej1; }
  }

  // ---- build B-table in LDS (coalesced lw reads, conflict-free writes) ----
  {
    int col = tid & 127;
    int kc2 = tid >> 7;  // 0/1: low/high half of kc range
#pragma unroll
    for (int i = 0; i < 8; ++i) {
      int kc = kc2 * 8 + i;
      bf16x8 t;
#pragma unroll
      for (int j = 0; j < 8; ++j)
        t[j] = (short)f2bf(lw[(size_t)(kc * 8 + j) * IN_CH + col]);
      *(bf16x8*)&blds[(kc * 128 + col) * 8] = t;
    }
  }
  __syncthreads();

  // ---- MFMA tile + score partials from f32 accumulators ----
  const int ccol = lane & 15;
  const int rg = lane >> 4;  // row group 0..3
  const int ko = rg * 8;
  const int row0 = n0 + wave * 16;
  int arow = row0 + ccol;
  if (arow >= N) arow = N - 1;  // clamped read; stores guarded
  const float* ap = x + (size_t)arow * IN_CH + ko;
  bf16x8 a[4];
#pragma unroll
  for (int kb = 0; kb < 4; ++kb) {
    float4 f0 = *(const float4*)(ap + kb * 32);
    float4 f1 = *(const float4*)(ap + kb * 32 + 4);
    bf16x8 t;
    t[0] = (short)f2bf(f0.x); t[1] = (short)f2bf(f0.y);
    t[2] = (short)f2bf(f0.z); t[3] = (short)f2bf(f0.w);
    t[4] = (short)f2bf(f1.x); t[5] = (short)f2bf(f1.y);
    t[6] = (short)f2bf(f1.z); t[7] = (short)f2bf(f1.w);
    a[kb] = t;
  }

  const int crow0 = row0 + rg * 4;
  const bf16x8* bls = (const bf16x8*)blds;
  float pI0[4] = {0,0,0,0}, pI1[4] = {0,0,0,0};
  float pJ0[4] = {0,0,0,0}, pJ1[4] = {0,0,0,0};
#pragma unroll
  for (int nt = 0; nt < 8; ++nt) {
    f32x4 acc = {0.f, 0.f, 0.f, 0.f};
#pragma unroll
    for (int kb = 0; kb < 4; ++kb)
      acc = __builtin_amdgcn_mfma_f32_16x16x32_bf16(
          a[kb], bls[(kb * 4 + rg) * 128 + nt * 16 + ccol], acc, 0, 0, 0);
    float ai = att_i[nt * 16 + ccol];
    float aj = att_j[nt * 16 + ccol];
#pragma unroll
    for (int rr = 0; rr < 4; ++rr) {
      int n = crow0 + rr;
      if (n < N) xhb[(size_t)n * IN_CH + nt * 16 + ccol] = f2bf(acc[rr]);
      if (nt < 4) {
        pI0[rr] = fmaf(acc[rr], ai, pI0[rr]);
        pJ0[rr] = fmaf(acc[rr], aj, pJ0[rr]);
      } else {
        pI1[rr] = fmaf(acc[rr], ai, pI1[rr]);
        pJ1[rr] = fmaf(acc[rr], aj, pJ1[rr]);
      }
    }
  }
  // reduce over the 16 columns held by this row group
#pragma unroll
  for (int off = 1; off < 16; off <<= 1) {
#pragma unroll
    for (int rr = 0; rr < 4; ++rr) {
      pI0[rr] += __shfl_xor(pI0[rr], off, 64);
      pI1[rr] += __shfl_xor(pI1[rr], off, 64);
      pJ0[rr] += __shfl_xor(pJ0[rr], off, 64);
      pJ1[rr] += __shfl_xor(pJ1[rr], off, 64);
    }
  }
  if (ccol == 0) {
#pragma unroll
    for (int rr = 0; rr < 4; ++rr) {
      int ln = wave * 16 + rg * 4 + rr;
      sxi0[ln] = pI0[rr]; sxi1[ln] = pI1[rr];
      sxj0[ln] = pJ0[rr]; sxj1[ln] = pJ1[rr];
    }
  }
  __syncthreads();

  // ---- combine + write per-node outputs ----
  if (tid < 64) {
    int n = n0 + tid;
    if (n < N) {
      float vi0 = sxi0[tid] + sei0[tid];
      float vi1 = sxi1[tid] + sei1[tid];
      float vj0 = sxj0[tid] + sej0[tid];
      float vj1 = sxj1[tid] + sej1[tid];
      si[n] = make_float2(vi0, vi1);
      sj[n] = make_float2(vj0, vj1);
      float a0 = vi0 + vj0;
      float a1 = vi1 + vj1;
      a0 = a0 > 0.f ? a0 : NEG_SLOPE * a0;
      a1 = a1 > 0.f ? a1 : NEG_SLOPE * a1;
      wself[n] = 1.f / (1.f + __expf(a1 - a0));
      wsum64[n] = 0ull;  // spill-fallback baseline
    }
  }
}

// ---------------------------------------------------------------------------
// Kernel 2 (bin): 1563 blocks, one 1024-edge chunk each, ~7.8 KB LDS.
// Counting-sort into 49 dst-range partitions. Round-7 changes vs round 6:
//  - si/sj gathers issued BEFORE hist+scan (latency hides under barriers).
//  - per-wave hist/cursor replicas (hist4/cur4[4][64]): same-address LDS
//    atomic serialization cut ~4x. Per-wave cursor bases derived from the
//    scan so each wave scatters into its own contiguous sub-range.
// Record = (dlocal10 << 22) | fx22(p0). Overflow -> packed u64 atomic.
// ---------------------------------------------------------------------------
__global__ __launch_bounds__(256) void bin_kernel(
    const int* __restrict__ esrc, const int* __restrict__ edst,
    const float2* __restrict__ si, const float2* __restrict__ sj,
    u32* __restrict__ brecs, int* __restrict__ gcur,
    u64* __restrict__ wsum64, int cap, int E) {
  __shared__ u32 recs[CEDGE];       // 4 KB
  __shared__ int hist4[4][64];      // 1 KB per-wave histograms
  __shared__ int cur4[4][64];       // 1 KB per-wave cursors (pre-based)
  __shared__ int scn[64], gbase[64];
  const int bid = blockIdx.x;
  const int tid = threadIdx.x;
  const int wave = tid >> 6;

  const long e0 = (long)bid * CEDGE;
  const int cnt = (int)min((long)CEDGE, (long)E - e0);

  hist4[tid >> 6][tid & 63] = 0;  // 256 slots, one per thread

  // edge-index loads + si/sj gathers issued EARLY (arrive during hist/scan)
  int dv[4];
  float2 av[4], bv[4];
#pragma unroll
  for (int k = 0; k < 4; ++k) {
    int r = (k << 8) + tid;
    dv[k] = (r < cnt) ? edst[e0 + r] : -1;
  }
#pragma unroll
  for (int k = 0; k < 4; ++k) {
    if (dv[k] >= 0) {
      int r = (k << 8) + tid;
      av[k] = si[esrc[e0 + r]];
      bv[k] = sj[dv[k]];
    }
  }
  __syncthreads();  // hist4 zeroed

#pragma unroll
  for (int k = 0; k < 4; ++k)
    if (dv[k] >= 0) atomicAdd(&hist4[wave][dv[k] >> BSHIFT], 1);
  __syncthreads();

  // wave-0: sum per-wave hists, shuffle prefix scan, per-wave cursor bases
  if (tid < 64) {
    int h0 = hist4[0][tid], h1 = hist4[1][tid];
    int h2 = hist4[2][tid], h3 = hist4[3][tid];
    int h = h0 + h1 + h2 + h3;
    int v = h;
#pragma unroll
    for (int off = 1; off < 64; off <<= 1) {
      int t = __shfl_up(v, off, 64);
      if (tid >= off) v += t;
    }
    int excl = v - h;
    scn[tid] = excl;
    gbase[tid] = (h > 0) ? atomicAdd(&gcur[tid], h) : 0;
    cur4[0][tid] = excl;
    cur4[1][tid] = excl + h0;
    cur4[2][tid] = excl + h0 + h1;
    cur4[3][tid] = excl + h0 + h1 + h2;
  }
  __syncthreads();

  // score + LDS scatter (gather data long since arrived)
#pragma unroll
  for (int k = 0; k < 4; ++k) {
    if (dv[k] >= 0) {
      float a0 = av[k].x + bv[k].x;
      float a1 = av[k].y + bv[k].y;
      a0 = a0 > 0.f ? a0 : NEG_SLOPE * a0;
      a1 = a1 > 0.f ? a1 : NEG_SLOPE * a1;
      float p0 = 1.f / (1.f + __expf(a1 - a0));
      u32 fx = (u32)fminf(p0 * FIX22 + 0.5f, 4194303.0f);  // 22-bit
      int pos = atomicAdd(&cur4[wave][dv[k] >> BSHIFT], 1);
      recs[pos] = ((u32)(dv[k] & 1023) << 22) | fx;
    }
  }
  __syncthreads();

  // coalesced writeout; partition via 6-iter binary search over scn
#pragma unroll
  for (int k = 0; k < 4; ++k) {
    int p = (k << 8) + tid;
    if (p < cnt) {
      int lo = 0, hi = 63;
#pragma unroll
      for (int it = 0; it < 6; ++it) {
        int mid = (lo + hi + 1) >> 1;
        if (scn[mid] <= p) lo = mid; else hi = mid - 1;
      }
      int b = lo;
      int gofs = gbase[b] + (p - scn[b]);
      u32 rec = recs[p];
      if (gofs < cap) {
        brecs[(size_t)b * cap + gofs] = rec;
      } else {  // rare spill: packed u64 device atomic
        atomicAdd(&wsum64[(b << BSHIFT) + (int)(rec >> 22)],
                  (1ull << 32) | (u64)(rec & 0x3FFFFFu));
      }
    }
  }
}

// ---------------------------------------------------------------------------
// Kernel 3 (reduce + out): XCD-affine mapping. All 16 filter-blocks of
// partition p get bid == p (mod 8), so under the bid%8 XCD round-robin they
// share one L2 and the partition's records are fetched from HBM once, not
// 16x (round-6 FETCH showed the cross-XCD re-fetch). Block (p,q) filters
// partition p's records for 64-node sub-bucket q into a 64-entry u64 LDS
// table, then writes out 64 nodes from bf16 xh + weights.
// ---------------------------------------------------------------------------
__global__ __launch_bounds__(256) void reduce_out_kernel(
    const unsigned short* __restrict__ xhb, const u64* __restrict__ wsum64,
    const float* __restrict__ wself, const u32* __restrict__ brecs,
    const int* __restrict__ gcur, int cap, float* __restrict__ out, int N,
    int nbkt) {
  __shared__ u64 tab[64];
  const int bid = blockIdx.x;
  const int xcd = bid & 7;        // XCD under round-robin dispatch
  const int t = bid >> 3;
  const int pg = t >> 4;          // partition group 0..6
  const int q = t & 15;           // 64-node sub-bucket
  const int p = xcd + (pg << 3);  // all q-blocks of p share this XCD
  if (p >= nbkt) return;
  const int n0 = (p << BSHIFT) + (q << 6);
  if (n0 >= N) return;
  const int tid = threadIdx.x;

  if (tid < 64) tab[tid] = 0ull;
  __syncthreads();

  const int cnt = min(gcur[p], cap);
  const u32* rp = brecs + (size_t)p * cap;
#pragma unroll 4
  for (int r = tid; r < cnt; r += 256) {
    u32 rec = rp[r];
    if ((int)(rec >> 28) == q)
      atomicAdd(&tab[(rec >> 22) & 63], (1ull << 32) | (u64)(rec & 0x3FFFFFu));
  }
  __syncthreads();

  const int nmax = min(64, N - n0);
  for (int it = tid; it < nmax * 16; it += 256) {
    int ln = it >> 4;
    int n = n0 + ln;
    int c4 = (it & 15) << 2;
    u64 acc = tab[ln] + wsum64[n];  // spill baseline shares packing
    float cnt_f = (float)(u32)(acc >> 32);
    float s0 = (float)(u32)(acc & 0xFFFFFFFFu) * (1.0f / FIX22);
    float ps = wself[n];
    float w0 = 0.5f * (s0 + ps);
    float w1 = 0.5f * ((cnt_f - s0) + (1.f - ps));
    ushort4 h0 = *(const ushort4*)&xhb[(size_t)n * IN_CH + c4];
    ushort4 h1 = *(const ushort4*)&xhb[(size_t)n * IN_CH + 64 + c4];
    float4 o;
    o.x = fmaf(bf2f(h0.x), w0, bf2f(h1.x) * w1);
    o.y = fmaf(bf2f(h0.y), w0, bf2f(h1.y) * w1);
    o.z = fmaf(bf2f(h0.z), w0, bf2f(h1.z) * w1);
    o.w = fmaf(bf2f(h0.w), w0, bf2f(h1.w) * w1);
    *(float4*)&out[(size_t)n * OUT_CH + c4] = o;
  }
}

extern "C" void kernel_launch(void* const* d_in, const int* in_sizes, int n_in,
                              void* d_out, int out_size, void* d_ws,
                              size_t ws_size, hipStream_t stream) {
  const float* x = (const float*)d_in[0];
  const float* emb = (const float*)d_in[1];
  const float* lw = (const float*)d_in[2];
  const float* att_i = (const float*)d_in[3];
  const float* att_j = (const float*)d_in[4];
  const float* aei = (const float*)d_in[5];
  const float* aej = (const float*)d_in[6];
  const int* esrc = (const int*)d_in[7];
  const int* edst = (const int*)d_in[8];
  float* out = (float*)d_out;

  int N = in_sizes[0] / IN_CH;  // 50000
  int E = in_sizes[7];          // 1600000
  int nbkt = (N + 1023) >> BSHIFT;       // 49 dst partitions
  int nchunk = (E + CEDGE - 1) / CEDGE;  // 1563 bin blocks
  int ntile = (N + 63) / 64;             // 782 node blocks
  int ngrp = (nbkt + 7) >> 3;            // 7 partition groups per XCD
  int nred = 8 * ngrp * 16;              // 896 reduce blocks (XCD-affine)

  char* ws = (char*)d_ws;
  u64* wsum64 = (u64*)ws;                            // N u64
  float2* si = (float2*)(wsum64 + N);                // N float2
  float2* sj = si + N;                               // N float2
  float* wself = (float*)(sj + N);                   // N f32
  unsigned short* xhb = (unsigned short*)(wself + N);  // N*128 bf16 (12.8 MB)
  int* gcur = (int*)(xhb + (size_t)N * IN_CH);       // 64 ints
  u32* brecs = (u32*)(gcur + 64);                    // nbkt * cap records

  size_t fixed = (size_t)((char*)brecs - ws);
  size_t avail = ws_size > fixed ? (ws_size - fixed) / 4 : 0;
  int cap = (int)(avail / (nbkt > 0 ? nbkt : 1));
  if (cap > CAPMAX) cap = CAPMAX;
  if (cap < 4096) cap = 4096;  // spill fallback keeps this correct anyway

  node_kernel<<<dim3(ntile), dim3(256), 0, stream>>>(
      x, emb, lw, att_i, att_j, aei, aej, xhb, si, sj, wself, wsum64, gcur, N);
  bin_kernel<<<dim3(nchunk), dim3(256), 0, stream>>>(esrc, edst, si, sj, brecs,
                                                     gcur, wsum64, cap, E);
  reduce_out_kernel<<<dim3(nred), dim3(256), 0, stream>>>(
      xhb, wsum64, wself, brecs, gcur, cap, out, N, nbkt);
}

// Round 8
// 159.827 us; speedup vs baseline: 2.6028x; 1.1658x over previous
//
#include <hip/hip_runtime.h>

#define IN_CH 128
#define OUT_CH 64
#define NEG_SLOPE 0.2f

#define BSHIFT 10       // 1024 nodes per partition
#define CEDGE 1024      // edges per bin block
#define CAPMAX 36864    // records per partition (mean 32.7K + ~22 sigma)
// p0 stored as 22-bit fixed point; u64 accumulate = (cnt<<32) | sum(fx22).
#define FIX22 4194304.0f

typedef short bf16x8 __attribute__((ext_vector_type(8)));
typedef float f32x4 __attribute__((ext_vector_type(4)));
typedef unsigned int u32x4 __attribute__((ext_vector_type(4)));
typedef unsigned long long u64;
typedef unsigned int u32;

__device__ __forceinline__ unsigned short f2bf(float f) {
  union { float f; unsigned u; } v;
  v.f = f;
  unsigned r = v.u + 0x7FFF + ((v.u >> 16) & 1);  // RNE
  return (unsigned short)(r >> 16);
}

__device__ __forceinline__ float bf2f(unsigned short h) {
  union { unsigned u; float f; } v;
  v.u = (unsigned)h << 16;
  return v.f;
}

// ---------------------------------------------------------------------------
// Kernel 1 (node): 782 blocks x 256. Per block (64 nodes):
//  - build bf16 B-table in LDS from lw (L2-resident).
//  - MFMA 64x128x128 tile: xh = x @ lw, x read ONCE.
//  - scores from the f32 accumulators + emb dot pass.
//  - writes xhb(bf16), si/sj, wself, seeds wsum64=0. Block 0 zeroes gcur.
// (unchanged from rounds 6/7 — verified passing)
// ---------------------------------------------------------------------------
__global__ __launch_bounds__(256) void node_kernel(
    const float* __restrict__ x, const float* __restrict__ emb,
    const float* __restrict__ lw, const float* __restrict__ att_i,
    const float* __restrict__ att_j, const float* __restrict__ aei,
    const float* __restrict__ aej, unsigned short* __restrict__ xhb,
    float2* __restrict__ si, float2* __restrict__ sj,
    float* __restrict__ wself, u64* __restrict__ wsum64,
    int* __restrict__ gcur, int N) {
  __shared__ unsigned short blds[16384];  // 32 KB B-table
  __shared__ float sxi0[64], sxi1[64], sxj0[64], sxj1[64];  // xh-part scores
  __shared__ float sei0[64], sei1[64], sej0[64], sej1[64];  // emb-part scores

  const int bid = blockIdx.x;
  const int tid = threadIdx.x;
  const int wave = tid >> 6;
  const int lane = tid & 63;
  const int n0 = bid * 64;

  if (bid == 0 && tid < 64) gcur[tid] = 0;

  // ---- emb dot pass: 4 threads per node, 16 channels each ----
  {
    int ln = tid >> 2;
    int q = tid & 3;
    int n = n0 + ln;
    float ei0 = 0.f, ei1 = 0.f, ej0 = 0.f, ej1 = 0.f;
    if (n < N) {
      const float* ep = emb + (size_t)n * OUT_CH + q * 16;
#pragma unroll
      for (int j4 = 0; j4 < 4; ++j4) {
        float4 e4 = *(const float4*)(ep + j4 * 4);
        float vals[4] = {e4.x, e4.y, e4.z, e4.w};
#pragma unroll
        for (int j = 0; j < 4; ++j) {
          int d = q * 16 + j4 * 4 + j;
          ei0 = fmaf(vals[j], aei[d], ei0);
          ei1 = fmaf(vals[j], aei[64 + d], ei1);
          ej0 = fmaf(vals[j], aej[d], ej0);
          ej1 = fmaf(vals[j], aej[64 + d], ej1);
        }
      }
    }
#pragma unroll
    for (int off = 1; off < 4; off <<= 1) {
      ei0 += __shfl_xor(ei0, off, 64);
      ei1 += __shfl_xor(ei1, off, 64);
      ej0 += __shfl_xor(ej0, off, 64);
      ej1 += __shfl_xor(ej1, off, 64);
    }
    if (q == 0) { sei0[ln] = ei0; sei1[ln] = ei1; sej0[ln] = ej0; sej1[ln] = ej1; }
  }

  // ---- build B-table in LDS (coalesced lw reads, conflict-free writes) ----
  {
    int col = tid & 127;
    int kc2 = tid >> 7;  // 0/1: low/high half of kc range
#pragma unroll
    for (int i = 0; i < 8; ++i) {
      int kc = kc2 * 8 + i;
      bf16x8 t;
#pragma unroll
      for (int j = 0; j < 8; ++j)
        t[j] = (short)f2bf(lw[(size_t)(kc * 8 + j) * IN_CH + col]);
      *(bf16x8*)&blds[(kc * 128 + col) * 8] = t;
    }
  }
  __syncthreads();

  // ---- MFMA tile + score partials from f32 accumulators ----
  const int ccol = lane & 15;
  const int rg = lane >> 4;  // row group 0..3
  const int ko = rg * 8;
  const int row0 = n0 + wave * 16;
  int arow = row0 + ccol;
  if (arow >= N) arow = N - 1;  // clamped read; stores guarded
  const float* ap = x + (size_t)arow * IN_CH + ko;
  bf16x8 a[4];
#pragma unroll
  for (int kb = 0; kb < 4; ++kb) {
    float4 f0 = *(const float4*)(ap + kb * 32);
    float4 f1 = *(const float4*)(ap + kb * 32 + 4);
    bf16x8 t;
    t[0] = (short)f2bf(f0.x); t[1] = (short)f2bf(f0.y);
    t[2] = (short)f2bf(f0.z); t[3] = (short)f2bf(f0.w);
    t[4] = (short)f2bf(f1.x); t[5] = (short)f2bf(f1.y);
    t[6] = (short)f2bf(f1.z); t[7] = (short)f2bf(f1.w);
    a[kb] = t;
  }

  const int crow0 = row0 + rg * 4;
  const bf16x8* bls = (const bf16x8*)blds;
  float pI0[4] = {0,0,0,0}, pI1[4] = {0,0,0,0};
  float pJ0[4] = {0,0,0,0}, pJ1[4] = {0,0,0,0};
#pragma unroll
  for (int nt = 0; nt < 8; ++nt) {
    f32x4 acc = {0.f, 0.f, 0.f, 0.f};
#pragma unroll
    for (int kb = 0; kb < 4; ++kb)
      acc = __builtin_amdgcn_mfma_f32_16x16x32_bf16(
          a[kb], bls[(kb * 4 + rg) * 128 + nt * 16 + ccol], acc, 0, 0, 0);
    float ai = att_i[nt * 16 + ccol];
    float aj = att_j[nt * 16 + ccol];
#pragma unroll
    for (int rr = 0; rr < 4; ++rr) {
      int n = crow0 + rr;
      if (n < N) xhb[(size_t)n * IN_CH + nt * 16 + ccol] = f2bf(acc[rr]);
      if (nt < 4) {
        pI0[rr] = fmaf(acc[rr], ai, pI0[rr]);
        pJ0[rr] = fmaf(acc[rr], aj, pJ0[rr]);
      } else {
        pI1[rr] = fmaf(acc[rr], ai, pI1[rr]);
        pJ1[rr] = fmaf(acc[rr], aj, pJ1[rr]);
      }
    }
  }
  // reduce over the 16 columns held by this row group
#pragma unroll
  for (int off = 1; off < 16; off <<= 1) {
#pragma unroll
    for (int rr = 0; rr < 4; ++rr) {
      pI0[rr] += __shfl_xor(pI0[rr], off, 64);
      pI1[rr] += __shfl_xor(pI1[rr], off, 64);
      pJ0[rr] += __shfl_xor(pJ0[rr], off, 64);
      pJ1[rr] += __shfl_xor(pJ1[rr], off, 64);
    }
  }
  if (ccol == 0) {
#pragma unroll
    for (int rr = 0; rr < 4; ++rr) {
      int ln = wave * 16 + rg * 4 + rr;
      sxi0[ln] = pI0[rr]; sxi1[ln] = pI1[rr];
      sxj0[ln] = pJ0[rr]; sxj1[ln] = pJ1[rr];
    }
  }
  __syncthreads();

  // ---- combine + write per-node outputs ----
  if (tid < 64) {
    int n = n0 + tid;
    if (n < N) {
      float vi0 = sxi0[tid] + sei0[tid];
      float vi1 = sxi1[tid] + sei1[tid];
      float vj0 = sxj0[tid] + sej0[tid];
      float vj1 = sxj1[tid] + sej1[tid];
      si[n] = make_float2(vi0, vi1);
      sj[n] = make_float2(vj0, vj1);
      float a0 = vi0 + vj0;
      float a1 = vi1 + vj1;
      a0 = a0 > 0.f ? a0 : NEG_SLOPE * a0;
      a1 = a1 > 0.f ? a1 : NEG_SLOPE * a1;
      wself[n] = 1.f / (1.f + __expf(a1 - a0));
      wsum64[n] = 0ull;  // spill-fallback baseline
    }
  }
}

// ---------------------------------------------------------------------------
// Kernel 2 (bin): 1563 blocks, one 1024-edge chunk each, ~7.8 KB LDS.
// Counting-sort into 49 dst-range partitions. Early si/sj gathers (latency
// hides under hist/scan), per-wave hist/cursor replicas. (unchanged from
// round 7 — below the profiling waterline)
// ---------------------------------------------------------------------------
__global__ __launch_bounds__(256) void bin_kernel(
    const int* __restrict__ esrc, const int* __restrict__ edst,
    const float2* __restrict__ si, const float2* __restrict__ sj,
    u32* __restrict__ brecs, int* __restrict__ gcur,
    u64* __restrict__ wsum64, int cap, int E) {
  __shared__ u32 recs[CEDGE];       // 4 KB
  __shared__ int hist4[4][64];      // 1 KB per-wave histograms
  __shared__ int cur4[4][64];       // 1 KB per-wave cursors (pre-based)
  __shared__ int scn[64], gbase[64];
  const int bid = blockIdx.x;
  const int tid = threadIdx.x;
  const int wave = tid >> 6;

  const long e0 = (long)bid * CEDGE;
  const int cnt = (int)min((long)CEDGE, (long)E - e0);

  hist4[tid >> 6][tid & 63] = 0;  // 256 slots, one per thread

  // edge-index loads + si/sj gathers issued EARLY (arrive during hist/scan)
  int dv[4];
  float2 av[4], bv[4];
#pragma unroll
  for (int k = 0; k < 4; ++k) {
    int r = (k << 8) + tid;
    dv[k] = (r < cnt) ? edst[e0 + r] : -1;
  }
#pragma unroll
  for (int k = 0; k < 4; ++k) {
    if (dv[k] >= 0) {
      int r = (k << 8) + tid;
      av[k] = si[esrc[e0 + r]];
      bv[k] = sj[dv[k]];
    }
  }
  __syncthreads();  // hist4 zeroed

#pragma unroll
  for (int k = 0; k < 4; ++k)
    if (dv[k] >= 0) atomicAdd(&hist4[wave][dv[k] >> BSHIFT], 1);
  __syncthreads();

  // wave-0: sum per-wave hists, shuffle prefix scan, per-wave cursor bases
  if (tid < 64) {
    int h0 = hist4[0][tid], h1 = hist4[1][tid];
    int h2 = hist4[2][tid], h3 = hist4[3][tid];
    int h = h0 + h1 + h2 + h3;
    int v = h;
#pragma unroll
    for (int off = 1; off < 64; off <<= 1) {
      int t = __shfl_up(v, off, 64);
      if (tid >= off) v += t;
    }
    int excl = v - h;
    scn[tid] = excl;
    gbase[tid] = (h > 0) ? atomicAdd(&gcur[tid], h) : 0;
    cur4[0][tid] = excl;
    cur4[1][tid] = excl + h0;
    cur4[2][tid] = excl + h0 + h1;
    cur4[3][tid] = excl + h0 + h1 + h2;
  }
  __syncthreads();

  // score + LDS scatter (gather data long since arrived)
#pragma unroll
  for (int k = 0; k < 4; ++k) {
    if (dv[k] >= 0) {
      float a0 = av[k].x + bv[k].x;
      float a1 = av[k].y + bv[k].y;
      a0 = a0 > 0.f ? a0 : NEG_SLOPE * a0;
      a1 = a1 > 0.f ? a1 : NEG_SLOPE * a1;
      float p0 = 1.f / (1.f + __expf(a1 - a0));
      u32 fx = (u32)fminf(p0 * FIX22 + 0.5f, 4194303.0f);  // 22-bit
      int pos = atomicAdd(&cur4[wave][dv[k] >> BSHIFT], 1);
      recs[pos] = ((u32)(dv[k] & 1023) << 22) | fx;
    }
  }
  __syncthreads();

  // coalesced writeout; partition via 6-iter binary search over scn
#pragma unroll
  for (int k = 0; k < 4; ++k) {
    int p = (k << 8) + tid;
    if (p < cnt) {
      int lo = 0, hi = 63;
#pragma unroll
      for (int it = 0; it < 6; ++it) {
        int mid = (lo + hi + 1) >> 1;
        if (scn[mid] <= p) lo = mid; else hi = mid - 1;
      }
      int b = lo;
      int gofs = gbase[b] + (p - scn[b]);
      u32 rec = recs[p];
      if (gofs < cap) {
        brecs[(size_t)b * cap + gofs] = rec;
      } else {  // rare spill: packed u64 device atomic
        atomicAdd(&wsum64[(b << BSHIFT) + (int)(rec >> 22)],
                  (1ull << 32) | (u64)(rec & 0x3FFFFFu));
      }
    }
  }
}

// ---------------------------------------------------------------------------
// Kernel 3 (reduce + out): XCD-affine mapping (kept — FETCH 31.6->9.7 MB in
// round 7). Round-8 change: the record scan uses explicit u32x4 vector
// loads, TWO in flight per iteration (8 records/thread/iter) — the round-7
// scalar loop exposed ~128 sequential L2 latencies per thread and was
// latency-bound (VALUBusy 9%, FETCH tiny, dur unchanged by the traffic fix).
// ---------------------------------------------------------------------------
__global__ __launch_bounds__(256) void reduce_out_kernel(
    const unsigned short* __restrict__ xhb, const u64* __restrict__ wsum64,
    const float* __restrict__ wself, const u32* __restrict__ brecs,
    const int* __restrict__ gcur, int cap, float* __restrict__ out, int N,
    int nbkt) {
  __shared__ u64 tab[64];
  const int bid = blockIdx.x;
  const int xcd = bid & 7;        // XCD under round-robin dispatch
  const int t = bid >> 3;
  const int pg = t >> 4;          // partition group
  const int q = t & 15;           // 64-node sub-bucket
  const int p = xcd + (pg << 3);  // all q-blocks of p share this XCD
  if (p >= nbkt) return;
  const int n0 = (p << BSHIFT) + (q << 6);
  if (n0 >= N) return;
  const int tid = threadIdx.x;

  if (tid < 64) tab[tid] = 0ull;
  __syncthreads();

  const int cnt = min(gcur[p], cap);
  const u32* rp = brecs + (size_t)p * cap;
  const u64 one = (1ull << 32);

  // main scan: 2048 records per block-iteration (2x dwordx4 per thread)
  int base = 0;
  for (; base + 2048 <= cnt; base += 2048) {
    u32x4 va = *(const u32x4*)(rp + base + tid * 4);
    u32x4 vb = *(const u32x4*)(rp + base + 1024 + tid * 4);
#pragma unroll
    for (int j = 0; j < 4; ++j) {
      u32 rec = va[j];
      if ((int)(rec >> 28) == q)
        atomicAdd(&tab[(rec >> 22) & 63], one | (u64)(rec & 0x3FFFFFu));
    }
#pragma unroll
    for (int j = 0; j < 4; ++j) {
      u32 rec = vb[j];
      if ((int)(rec >> 28) == q)
        atomicAdd(&tab[(rec >> 22) & 63], one | (u64)(rec & 0x3FFFFFu));
    }
  }
  // tail (< 2048 records), scalar
  for (int r = base + tid; r < cnt; r += 256) {
    u32 rec = rp[r];
    if ((int)(rec >> 28) == q)
      atomicAdd(&tab[(rec >> 22) & 63], one | (u64)(rec & 0x3FFFFFu));
  }
  __syncthreads();

  const int nmax = min(64, N - n0);
  for (int it = tid; it < nmax * 16; it += 256) {
    int ln = it >> 4;
    int n = n0 + ln;
    int c4 = (it & 15) << 2;
    u64 acc = tab[ln] + wsum64[n];  // spill baseline shares packing
    float cnt_f = (float)(u32)(acc >> 32);
    float s0 = (float)(u32)(acc & 0xFFFFFFFFu) * (1.0f / FIX22);
    float ps = wself[n];
    float w0 = 0.5f * (s0 + ps);
    float w1 = 0.5f * ((cnt_f - s0) + (1.f - ps));
    ushort4 h0 = *(const ushort4*)&xhb[(size_t)n * IN_CH + c4];
    ushort4 h1 = *(const ushort4*)&xhb[(size_t)n * IN_CH + 64 + c4];
    float4 o;
    o.x = fmaf(bf2f(h0.x), w0, bf2f(h1.x) * w1);
    o.y = fmaf(bf2f(h0.y), w0, bf2f(h1.y) * w1);
    o.z = fmaf(bf2f(h0.z), w0, bf2f(h1.z) * w1);
    o.w = fmaf(bf2f(h0.w), w0, bf2f(h1.w) * w1);
    *(float4*)&out[(size_t)n * OUT_CH + c4] = o;
  }
}

extern "C" void kernel_launch(void* const* d_in, const int* in_sizes, int n_in,
                              void* d_out, int out_size, void* d_ws,
                              size_t ws_size, hipStream_t stream) {
  const float* x = (const float*)d_in[0];
  const float* emb = (const float*)d_in[1];
  const float* lw = (const float*)d_in[2];
  const float* att_i = (const float*)d_in[3];
  const float* att_j = (const float*)d_in[4];
  const float* aei = (const float*)d_in[5];
  const float* aej = (const float*)d_in[6];
  const int* esrc = (const int*)d_in[7];
  const int* edst = (const int*)d_in[8];
  float* out = (float*)d_out;

  int N = in_sizes[0] / IN_CH;  // 50000
  int E = in_sizes[7];          // 1600000
  int nbkt = (N + 1023) >> BSHIFT;       // 49 dst partitions
  int nchunk = (E + CEDGE - 1) / CEDGE;  // 1563 bin blocks
  int ntile = (N + 63) / 64;             // 782 node blocks
  int ngrp = (nbkt + 7) >> 3;            // 7 partition groups per XCD
  int nred = 8 * ngrp * 16;              // 896 reduce blocks (XCD-affine)

  char* ws = (char*)d_ws;
  u64* wsum64 = (u64*)ws;                            // N u64
  float2* si = (float2*)(wsum64 + N);                // N float2
  float2* sj = si + N;                               // N float2
  float* wself = (float*)(sj + N);                   // N f32
  unsigned short* xhb = (unsigned short*)(wself + N);  // N*128 bf16 (12.8 MB)
  int* gcur = (int*)(xhb + (size_t)N * IN_CH);       // 64 ints
  u32* brecs = (u32*)(gcur + 64);                    // nbkt * cap records

  size_t fixed = (size_t)((char*)brecs - ws);
  size_t avail = ws_size > fixed ? (ws_size - fixed) / 4 : 0;
  int cap = (int)(avail / (nbkt > 0 ? nbkt : 1));
  if (cap > CAPMAX) cap = CAPMAX;
  if (cap < 4096) cap = 4096;  // spill fallback keeps this correct anyway
  cap &= ~3;                   // 16B-aligned record regions for u32x4 loads

  node_kernel<<<dim3(ntile), dim3(256), 0, stream>>>(
      x, emb, lw, att_i, att_j, aei, aej, xhb, si, sj, wself, wsum64, gcur, N);
  bin_kernel<<<dim3(nchunk), dim3(256), 0, stream>>>(esrc, edst, si, sj, brecs,
                                                     gcur, wsum64, cap, E);
  reduce_out_kernel<<<dim3(nred), dim3(256), 0, stream>>>(
      xhb, wsum64, wself, brecs, gcur, cap, out, N, nbkt);
}